// Round 6
// baseline (1257.780 us; speedup 1.0000x reference)
//
#include <hip/hip_runtime.h>
#include <cmath>

#define B_  16
#define SEQ 2048
#define DIM 1024
#define LDST 40              // legacy stride for g1 LDS tiles

typedef short  short8 __attribute__((ext_vector_type(8)));
typedef short  sh4    __attribute__((ext_vector_type(4)));
typedef float  f32x4  __attribute__((ext_vector_type(4)));

__device__ __forceinline__ unsigned short f2bf(float x) {
  unsigned u = __builtin_bit_cast(unsigned, x);
  return (unsigned short)((u + 0x7fffu + ((u >> 16) & 1u)) >> 16);   // RNE
}
__device__ __forceinline__ float bf2f(unsigned short h) {
  unsigned u = ((unsigned)h) << 16;
  return __builtin_bit_cast(float, u);
}

// async global->LDS, 16B per lane; LDS dest = wave-uniform base + lane*16
__device__ __forceinline__ void gl16(const void* g, void* l) {
  __builtin_amdgcn_global_load_lds(
      (const __attribute__((address_space(1))) void*)g,
      (__attribute__((address_space(3))) void*)l, 16, 0, 0);
}

// ---------------------------------------------------------------------------
// cvt_ctx: ctx f32 -> ctx_hi/ctx_lo bf16 planes (into d_out comp region)
// ---------------------------------------------------------------------------
__global__ __launch_bounds__(256) void cvt_ctx(const float* __restrict__ X,
                                               unsigned short* __restrict__ hi,
                                               unsigned short* __restrict__ lo) {
  const size_t N8 = (size_t)B_ * SEQ * DIM / 8;
  for (size_t i = (size_t)blockIdx.x * 256 + threadIdx.x; i < N8;
       i += (size_t)gridDim.x * 256) {
    const size_t base = i * 8;
    float4 a = *(const float4*)&X[base];
    float4 c = *(const float4*)&X[base + 4];
    const float xs[8] = {a.x, a.y, a.z, a.w, c.x, c.y, c.z, c.w};
    short8 h, l;
#pragma unroll
    for (int j = 0; j < 8; ++j) {
      unsigned short hh = f2bf(xs[j]);
      h[j] = (short)hh;
      l[j] = (short)f2bf(xs[j] - bf2f(hh));
    }
    *(short8*)&hi[base] = h;
    *(short8*)&lo[base] = l;
  }
}

// ---------------------------------------------------------------------------
// t_ctx: ctxT[b][d][s] bf16 = ctx[b][s][d]  (64x64 LDS tile transpose)
// ---------------------------------------------------------------------------
__global__ __launch_bounds__(256) void t_ctx(const float* __restrict__ X,
                                             unsigned short* __restrict__ T) {
  __shared__ unsigned short L[64 * 72];
  const int t = threadIdx.x;
  const int d0 = blockIdx.x * 64, s0 = blockIdx.y * 64, b = blockIdx.z;
#pragma unroll
  for (int p = 0; p < 4; ++p) {
    const int sl = (t >> 4) + p * 16, d4 = (t & 15) * 4;
    float4 v = *(const float4*)&X[((size_t)b * SEQ + s0 + sl) * DIM + d0 + d4];
    sh4 o = {(short)f2bf(v.x), (short)f2bf(v.y), (short)f2bf(v.z), (short)f2bf(v.w)};
    *(sh4*)&L[sl * 72 + d4] = o;
  }
  __syncthreads();
#pragma unroll
  for (int p = 0; p < 4; ++p) {
    const int dl = (t >> 4) + p * 16, s4 = (t & 15) * 4;
    sh4 o = {(short)L[(s4 + 0) * 72 + dl], (short)L[(s4 + 1) * 72 + dl],
             (short)L[(s4 + 2) * 72 + dl], (short)L[(s4 + 3) * 72 + dl]};
    *(sh4*)&T[((size_t)b * DIM + d0 + dl) * SEQ + s0 + s4] = o;
  }
}

// ---------------------------------------------------------------------------
// G1: z[r][d] = sum_e query[r][e] * W[d][e],  r = q*B_+b  (unchanged)
// ---------------------------------------------------------------------------
__global__ __launch_bounds__(256) void g1_z(const float* __restrict__ Q,
                                            const float* __restrict__ W,
                                            unsigned short* __restrict__ zhi,
                                            unsigned short* __restrict__ zlo) {
  __shared__ unsigned short Ah[128 * LDST], Al[128 * LDST];
  __shared__ unsigned short Bh[128 * LDST], Bl[128 * LDST];
  const int tid = threadIdx.x;
  const int m0 = blockIdx.y * 128, n0 = blockIdx.x * 128;
  const int wave = tid >> 6, lane = tid & 63;
  const int wm = (wave >> 1) * 64, wn = (wave & 1) * 64;
  const int rl = tid & 127;

  const float* srow = (tid < 128) ? Q + (size_t)(m0 + rl) * DIM
                                  : W + (size_t)(n0 + rl) * DIM;
  unsigned short* th = (tid < 128) ? Ah : Bh;
  unsigned short* tl = (tid < 128) ? Al : Bl;

  f32x4 acc[4][4];
#pragma unroll
  for (int i = 0; i < 4; ++i)
#pragma unroll
    for (int j = 0; j < 4; ++j) acc[i][j] = (f32x4){0.f, 0.f, 0.f, 0.f};

  for (int kc = 0; kc < DIM; kc += 32) {
    float4 fv[8];
#pragma unroll
    for (int j = 0; j < 8; ++j) fv[j] = *(const float4*)&srow[kc + j * 4];
    __syncthreads();
    short8 hv[4], lv[4];
#pragma unroll
    for (int j = 0; j < 8; ++j) {
      const float x[4] = {fv[j].x, fv[j].y, fv[j].z, fv[j].w};
#pragma unroll
      for (int c = 0; c < 4; ++c) {
        unsigned short h = f2bf(x[c]);
        unsigned short l = f2bf(x[c] - bf2f(h));
        hv[j >> 1][(j & 1) * 4 + c] = (short)h;
        lv[j >> 1][(j & 1) * 4 + c] = (short)l;
      }
    }
#pragma unroll
    for (int j = 0; j < 4; ++j) {
      *(short8*)&th[rl * LDST + j * 8] = hv[j];
      *(short8*)&tl[rl * LDST + j * 8] = lv[j];
    }
    __syncthreads();

    short8 ah[4], al[4], bh[4], bl[4];
#pragma unroll
    for (int f = 0; f < 4; ++f) {
      const int ao = (wm + f * 16 + (lane & 15)) * LDST + (lane >> 4) * 8;
      const int bo = (wn + f * 16 + (lane & 15)) * LDST + (lane >> 4) * 8;
      ah[f] = *(const short8*)&Ah[ao];  al[f] = *(const short8*)&Al[ao];
      bh[f] = *(const short8*)&Bh[bo];  bl[f] = *(const short8*)&Bl[bo];
    }
#pragma unroll
    for (int i = 0; i < 4; ++i)
#pragma unroll
      for (int j = 0; j < 4; ++j) {
        acc[i][j] = __builtin_amdgcn_mfma_f32_16x16x32_bf16(ah[i], bh[j], acc[i][j], 0, 0, 0);
        acc[i][j] = __builtin_amdgcn_mfma_f32_16x16x32_bf16(al[i], bh[j], acc[i][j], 0, 0, 0);
        acc[i][j] = __builtin_amdgcn_mfma_f32_16x16x32_bf16(ah[i], bl[j], acc[i][j], 0, 0, 0);
      }
  }
#pragma unroll
  for (int i = 0; i < 4; ++i)
#pragma unroll
    for (int j = 0; j < 4; ++j)
#pragma unroll
      for (int r = 0; r < 4; ++r) {
        const int row = m0 + wm + i * 16 + (lane >> 4) * 4 + r;
        const int col = n0 + wn + j * 16 + (lane & 15);
        const float v = acc[i][j][r];
        const unsigned short h = f2bf(v);
        zhi[(size_t)row * DIM + col] = h;
        zlo[(size_t)row * DIM + col] = f2bf(v - bf2f(h));
      }
}

// ---------------------------------------------------------------------------
// G2: scores = z . ctx^T per batch; XOR-swizzled LDS (block ^= (row>>1)&3),
// applied via pre-swizzled global source (gl16 writes linearly, rule #21).
// ---------------------------------------------------------------------------
#define G2GRID (16 * 16 * B_)
__global__ __launch_bounds__(256) void g2_scores(const unsigned short* __restrict__ zhi,
                                                 const unsigned short* __restrict__ zlo,
                                                 const unsigned short* __restrict__ chi,
                                                 const unsigned short* __restrict__ clo,
                                                 float* __restrict__ Sc) {
  __shared__ unsigned short Sh[128 * 32], Sl[128 * 32];   // ctx tiles (s-rows)
  __shared__ unsigned short Qh[128 * 32], Ql[128 * 32];   // z tiles (q-rows)
  const int tid = threadIdx.x, lane = tid & 63, wave = tid >> 6;

  const int lin = blockIdx.x;
  const int swz = (lin & 7) * (G2GRID / 8) + (lin >> 3);
  const int s0 = (swz & 15) * 128;
  const int q0 = ((swz >> 4) & 15) * 128;
  const int b  = swz >> 8;

  const int wm = (wave >> 1) * 64;   // s
  const int wn = (wave & 1) * 64;    // q

  const int r_sub = lane >> 2;                              // row within 16-row chunk
  const int c_sub = (((lane & 3) ^ ((lane >> 3) & 3))) * 8; // swizzled 16B block

  f32x4 acc[4][4];
#pragma unroll
  for (int i = 0; i < 4; ++i)
#pragma unroll
    for (int j = 0; j < 4; ++j) acc[i][j] = (f32x4){0.f, 0.f, 0.f, 0.f};

  for (int kc = 0; kc < DIM; kc += 32) {
    if (wave == 0) {
#pragma unroll
      for (int it = 0; it < 8; ++it)
        gl16(&chi[((size_t)b * SEQ + s0 + it * 16 + r_sub) * DIM + kc + c_sub], &Sh[it * 512]);
    } else if (wave == 1) {
#pragma unroll
      for (int it = 0; it < 8; ++it)
        gl16(&clo[((size_t)b * SEQ + s0 + it * 16 + r_sub) * DIM + kc + c_sub], &Sl[it * 512]);
    } else if (wave == 2) {
#pragma unroll
      for (int it = 0; it < 8; ++it)
        gl16(&zhi[((size_t)(q0 + it * 16 + r_sub) * B_ + b) * DIM + kc + c_sub], &Qh[it * 512]);
    } else {
#pragma unroll
      for (int it = 0; it < 8; ++it)
        gl16(&zlo[((size_t)(q0 + it * 16 + r_sub) * B_ + b) * DIM + kc + c_sub], &Ql[it * 512]);
    }
    __syncthreads();

    short8 sh_[4], sl_[4], qh_[4], ql_[4];
#pragma unroll
    for (int f = 0; f < 4; ++f) {
      const int ra = wm + f * 16 + (lane & 15);
      const int rb = wn + f * 16 + (lane & 15);
      const int so = ra * 32 + (((lane >> 4) ^ ((ra >> 1) & 3))) * 8;
      const int qo = rb * 32 + (((lane >> 4) ^ ((rb >> 1) & 3))) * 8;
      sh_[f] = *(const short8*)&Sh[so];  sl_[f] = *(const short8*)&Sl[so];
      qh_[f] = *(const short8*)&Qh[qo];  ql_[f] = *(const short8*)&Ql[qo];
    }
#pragma unroll
    for (int i = 0; i < 4; ++i)
#pragma unroll
      for (int j = 0; j < 4; ++j) {
        acc[i][j] = __builtin_amdgcn_mfma_f32_16x16x32_bf16(sh_[i], qh_[j], acc[i][j], 0, 0, 0);
        acc[i][j] = __builtin_amdgcn_mfma_f32_16x16x32_bf16(sl_[i], qh_[j], acc[i][j], 0, 0, 0);
        acc[i][j] = __builtin_amdgcn_mfma_f32_16x16x32_bf16(sh_[i], ql_[j], acc[i][j], 0, 0, 0);
      }
    __syncthreads();
  }

#pragma unroll
  for (int i = 0; i < 4; ++i)
#pragma unroll
    for (int j = 0; j < 4; ++j) {
      const int s = s0 + wm + i * 16 + (lane >> 4) * 4;
      const int q = q0 + wn + j * 16 + (lane & 15);
      f32x4 v = {acc[i][j][0], acc[i][j][1], acc[i][j][2], acc[i][j][3]};
      __builtin_nontemporal_store(v, (f32x4*)&Sc[((size_t)q * B_ + b) * SEQ + s]);
    }
}

// ---------------------------------------------------------------------------
// softmax: in-place on d_out attn region (no bf16 side copy anymore)
// ---------------------------------------------------------------------------
__global__ __launch_bounds__(256) void kernel_softmax(float* __restrict__ attn,
                                                      const int* __restrict__ mask) {
  const int row = blockIdx.x;       // q*B_ + b
  const int b = row & (B_ - 1);
  float* p = attn + (size_t)row * SEQ;
  const int* m = mask + (size_t)b * SEQ;
  const int t = threadIdx.x;

  float v[8];
  float mx = -INFINITY;
#pragma unroll
  for (int i = 0; i < 8; ++i) {
    const int s = t + i * 256;
    float x = p[s];
    x = m[s] ? -1e30f : x;
    v[i] = x;
    mx = fmaxf(mx, x);
  }
#pragma unroll
  for (int off = 32; off > 0; off >>= 1) mx = fmaxf(mx, __shfl_xor(mx, off));
  __shared__ float redmax[4];
  __shared__ float redsum[4];
  if ((t & 63) == 0) redmax[t >> 6] = mx;
  __syncthreads();
  mx = fmaxf(fmaxf(redmax[0], redmax[1]), fmaxf(redmax[2], redmax[3]));

  float sum = 0.f;
#pragma unroll
  for (int i = 0; i < 8; ++i) {
    v[i] = __expf(v[i] - mx);
    sum += v[i];
  }
#pragma unroll
  for (int off = 32; off > 0; off >>= 1) sum += __shfl_xor(sum, off);
  if ((t & 63) == 0) redsum[t >> 6] = sum;
  __syncthreads();
  sum = (redsum[0] + redsum[1]) + (redsum[2] + redsum[3]);

  const bool allmasked = (mx < -1e29f);
  const float inv = allmasked ? 0.f : 1.f / sum;
#pragma unroll
  for (int i = 0; i < 8; ++i) p[t + i * 256] = v[i] * inv;
}

// ---------------------------------------------------------------------------
// G3 (rebuilt): comp[q][b][d] = sum_s attn[q][b][s] * ctx[b][s][d]
// A/M-operand = ctxT d-rows (gl16, swizzled source) -> D rows = d contiguous.
// B/N-operand = attn q-rows, f32 read coalesced -> cvt bf16 -> swizzled ds_write.
// ---------------------------------------------------------------------------
__global__ __launch_bounds__(256) void g3_comp(const float* __restrict__ attn,
                                               const unsigned short* __restrict__ ctxT,
                                               float* __restrict__ Out) {
  __shared__ unsigned short Ad[128 * 32];   // ctxT tile (d-rows)
  __shared__ unsigned short Bq[128 * 32];   // attn tile (q-rows, bf16)
  const int tid = threadIdx.x, lane = tid & 63, wave = tid >> 6;
  const int b = blockIdx.z;
  const int d0 = blockIdx.x * 128, q0 = blockIdx.y * 128;
  const int wm = (wave >> 1) * 64;   // d
  const int wn = (wave & 1) * 64;    // q

  const int r_sub = lane >> 2;
  const int c_sub = (((lane & 3) ^ ((lane >> 3) & 3))) * 8;

  const int qrow = tid >> 1, shalf = (tid & 1) * 16;
  const float* arow = attn + ((size_t)(q0 + qrow) * B_ + b) * SEQ;
  const int qsw = (qrow >> 1) & 3;
  const int blk_base = (tid & 1) * 2;
  unsigned short* bdst0 = &Bq[qrow * 32 + ((blk_base + 0) ^ qsw) * 8];
  unsigned short* bdst1 = &Bq[qrow * 32 + ((blk_base + 1) ^ qsw) * 8];

  f32x4 acc[4][4];
#pragma unroll
  for (int i = 0; i < 4; ++i)
#pragma unroll
    for (int j = 0; j < 4; ++j) acc[i][j] = (f32x4){0.f, 0.f, 0.f, 0.f};

  for (int kc = 0; kc < SEQ; kc += 32) {
    // B: attn f32 -> regs (issue early)
    float4 fv[4];
#pragma unroll
    for (int j = 0; j < 4; ++j) fv[j] = *(const float4*)&arow[kc + shalf + j * 4];
    // A: ctxT gl16, this wave stages rows [wave*32, wave*32+32)
#pragma unroll
    for (int i = 0; i < 2; ++i) {
      const int rb = wave * 32 + i * 16;
      gl16(&ctxT[((size_t)b * DIM + d0 + rb + r_sub) * SEQ + kc + c_sub], &Ad[rb * 32]);
    }
    // cvt + swizzled LDS write of B
    short8 bv0, bv1;
#pragma unroll
    for (int j = 0; j < 4; ++j) {
      const float x[4] = {fv[j].x, fv[j].y, fv[j].z, fv[j].w};
#pragma unroll
      for (int c = 0; c < 4; ++c) {
        const int e = j * 4 + c;
        if (e < 8) bv0[e] = (short)f2bf(x[c]);
        else       bv1[e - 8] = (short)f2bf(x[c]);
      }
    }
    *(short8*)bdst0 = bv0;
    *(short8*)bdst1 = bv1;
    __syncthreads();

    short8 af[4], bf_[4];
#pragma unroll
    for (int f = 0; f < 4; ++f) {
      const int ra = wm + f * 16 + (lane & 15);
      const int rb = wn + f * 16 + (lane & 15);
      af[f]  = *(const short8*)&Ad[ra * 32 + (((lane >> 4) ^ ((ra >> 1) & 3))) * 8];
      bf_[f] = *(const short8*)&Bq[rb * 32 + (((lane >> 4) ^ ((rb >> 1) & 3))) * 8];
    }
#pragma unroll
    for (int i = 0; i < 4; ++i)
#pragma unroll
      for (int j = 0; j < 4; ++j)
        acc[i][j] = __builtin_amdgcn_mfma_f32_16x16x32_bf16(af[i], bf_[j], acc[i][j], 0, 0, 0);
    __syncthreads();
  }

#pragma unroll
  for (int i = 0; i < 4; ++i)
#pragma unroll
    for (int j = 0; j < 4; ++j) {
      const int d = d0 + wm + i * 16 + (lane >> 4) * 4;
      const int q = q0 + wn + j * 16 + (lane & 15);
      f32x4 v = {acc[i][j][0], acc[i][j][1], acc[i][j][2], acc[i][j][3]};
      __builtin_nontemporal_store(v, (f32x4*)&Out[((size_t)q * B_ + b) * DIM + d]);
    }
}

extern "C" void kernel_launch(void* const* d_in, const int* in_sizes, int n_in,
                              void* d_out, int out_size, void* d_ws, size_t ws_size,
                              hipStream_t stream) {
  const float* context = (const float*)d_in[0];   // [B, SEQ, DIM]
  const float* query   = (const float*)d_in[1];   // [SEQ, B, DIM]
  const float* W       = (const float*)d_in[2];   // [DIM, DIM]
  const int*   mask    = (const int*)d_in[3];     // [B, SEQ] bool->int32

  float* attn = (float*)d_out;                     // [SEQ, B, SEQ]  (256 MiB)
  float* comp = attn + (size_t)SEQ * B_ * SEQ;     // [SEQ, B, DIM]  (128 MiB)

  // ctx bf16 hi/lo planes live in the comp region until G3 overwrites it
  unsigned short* chi = (unsigned short*)comp;                     // 64 MiB
  unsigned short* clo = chi + (size_t)B_ * SEQ * DIM;              // 64 MiB

  unsigned short* zhi  = (unsigned short*)d_ws;                    // 64 MiB
  unsigned short* zlo  = zhi + (size_t)SEQ * B_ * DIM;             // 64 MiB
  unsigned short* ctxT = (unsigned short*)d_ws;                    // reuses z after G2

  // 0) ctx -> bf16 hi/lo planes (comp region; dead until G3)
  cvt_ctx<<<dim3(4096), 256, 0, stream>>>(context, chi, clo);
  // 1) z = W @ query (flat rows), bf16x2
  g1_z<<<dim3(DIM / 128, (SEQ * B_) / 128), 256, 0, stream>>>(query, W, zhi, zlo);
  // 2) scores -> attn region (swizzled LDS)
  g2_scores<<<dim3(G2GRID), 256, 0, stream>>>(zhi, zlo, chi, clo, attn);
  // 2b) ctxT bf16 [b][d][s] into d_ws (z is dead now)
  t_ctx<<<dim3(DIM / 64, SEQ / 64, B_), 256, 0, stream>>>(context, ctxT);
  // 3) masked softmax in place
  kernel_softmax<<<dim3(SEQ * B_), 256, 0, stream>>>(attn, mask);
  // 4) comp = attn @ ctx via ctxT (swizzled LDS)
  g3_comp<<<dim3(DIM / 128, SEQ / 128, B_), 256, 0, stream>>>(attn, ctxT, comp);
}